// Round 2
// 149.800 us; speedup vs baseline: 1.0012x; 1.0012x over previous
//
#include <hip/hip_runtime.h>
#include <hip/hip_cooperative_groups.h>
#include <math.h>

namespace cg = cooperative_groups;

#define NTYPE   4
#define NWAVE   8
#define NORBIT  128
#define NEIGH   64
#define NB      32
#define NATOM   256
#define NPP     (NATOM * NEIGH)   /* 16384 pairs per batch */
#define NPAIR   (NB * NPP)        /* 524288 */
#define TOTATOM (NB * NATOM)      /* 8192  */
#define NPARA   13                /* 1 + 3 + 9 */

/* ---- fused (cooperative) config ---- */
#define CHUNK   512               /* pairs per sort chunk */
#define BPB     32                /* chunks per batch */
#define NBLK    (NB * BPB)        /* 1024 blocks — 4/CU co-resident */
#define APB     (TOTATOM / NBLK)  /* 8 atoms per block in density phase */

/* ---- fallback (separate-kernel) config — the proven 148.9us baseline ---- */
#define FB_CHUNK  2048
#define FB_BPB    8
#define FB_NBLK   (NB * FB_BPB)   /* 256 */

__device__ __forceinline__ float fast_tanh(float x) {
    float ax = fabsf(x);
    float e  = __expf(-2.0f * ax);
    float r  = (1.0f - e) / (1.0f + e);
    return copysignf(r, x);
}

/* ======================= fused cooperative kernel ======================== */
__global__ __launch_bounds__(256, 4) void k_fused(
    const int* __restrict__ atom_index, const float* __restrict__ cart,
    const float* __restrict__ shifts, const int* __restrict__ species,
    const float* __restrict__ rs, const float* __restrict__ inta,
    const float* __restrict__ params, const float* __restrict__ hyper,
    const float* __restrict__ W0, const float* __restrict__ E0,
    const float* __restrict__ W1, const float* __restrict__ E1,
    float* __restrict__ density_out, float4* __restrict__ rec,
    float* __restrict__ coeffA, float* __restrict__ coeffB,
    int* __restrict__ offs, int* __restrict__ histpart,
    int* __restrict__ startpart)
{
    cg::grid_group grid = cg::this_grid();
    const int bl = blockIdx.x, t = threadIdx.x;
    const int b = bl >> 5, c = bl & 31;       // batch, chunk-within-batch
    const int base = b * NPP + c * CHUNK;

    __shared__ int   ibuf[NATOM];             // hist in phase A, scan in phase B
    __shared__ int   cur[NATOM];
    __shared__ float cx[NATOM], cy[NATOM], cz[NATOM];
    __shared__ int   spl[NATOM];
    __shared__ float lds_S[4][NWAVE * 16];

    // ---- Phase A: per-chunk histogram (all 1024 blocks) ---------------------
    ibuf[t] = 0;
    __syncthreads();
#pragma unroll
    for (int k = 0; k < CHUNK / 256; k++)
        atomicAdd(&ibuf[atom_index[base + t + k * 256]], 1);
    __syncthreads();
    histpart[bl * NATOM + t] = ibuf[t];
    __threadfence();
    grid.sync();
    __threadfence();

    // ---- Phase B: per-batch merge + scan + per-chunk cursors + coeff init ---
    if (bl < NB) {
        int h[BPB];
        int tot = 0;
#pragma unroll
        for (int c2 = 0; c2 < BPB; c2++) {
            h[c2] = histpart[(bl * BPB + c2) * NATOM + t];
            tot += h[c2];
        }
        ibuf[t] = tot;
        __syncthreads();
        for (int d = 1; d < NATOM; d <<= 1) {
            int v = (t >= d) ? ibuf[t - d] : 0;
            __syncthreads();
            ibuf[t] += v;
            __syncthreads();
        }
        int run = bl * NPP + ibuf[t] - tot;   // exclusive prefix within batch
        offs[bl * NATOM + t] = run;
        if (bl == 0 && t == 0) offs[TOTATOM] = NPAIR;
#pragma unroll
        for (int c2 = 0; c2 < BPB; c2++) {
            startpart[(bl * BPB + c2) * NATOM + t] = run;
            run += h[c2];
        }
        int a = bl * NATOM + t;
        int sp = species[a];
#pragma unroll
        for (int w = 0; w < NWAVE; w++)
            coeffA[a * NWAVE + w] = params[sp * NWAVE + w];
    }
    __threadfence();
    grid.sync();
    __threadfence();

    // ---- Phase C: scatter (all 1024 blocks) ---------------------------------
    cur[t] = startpart[bl * NATOM + t];
    const int ag = b * NATOM + t;
    cx[t] = cart[ag * 3 + 0];
    cy[t] = cart[ag * 3 + 1];
    cz[t] = cart[ag * 3 + 2];
    spl[t] = species[ag];
    __syncthreads();
#pragma unroll
    for (int k = 0; k < CHUNK / 256; k++) {
        int p = base + t + k * 256;
        int i = atom_index[p];
        int j = atom_index[NPAIR + p];
        float dx = cx[i] - cx[j] + shifts[p * 3 + 0];
        float dy = cy[i] - cy[j] + shifts[p * 3 + 1];
        float dz = cz[i] - cz[j] + shifts[p * 3 + 2];
        int jg = b * NATOM + j;
        int pos = atomicAdd(&cur[i], 1);
        rec[pos] = make_float4(dx, dy, dz, __int_as_float(jg | (spl[j] << 16)));
    }
    __threadfence();
    grid.sync();
    __threadfence();

    // ---- Phases D/E/F: three fused obtain() + coeff-update rounds -----------
    const int wv = t >> 6;
    const int lane = t & 63;
    const int pl = lane >> 3;       // pair sub-lane 0..7
    const int w  = lane & 7;        // wave channel 0..7
    const int o0 = lane, o1 = lane + 64;

    const float rs0 = rs[w],      rs1 = rs[8 + w],  rs2 = rs[16 + w], rs3 = rs[24 + w];
    const float in0 = inta[w],    in1 = inta[8 + w], in2 = inta[16 + w], in3 = inta[24 + w];

    for (int round = 0; round < 3; round++) {
        const float* cin  = (round == 1) ? coeffB : coeffA;
        float*       cout = (round == 0) ? coeffB : coeffA;
        const float* Wm   = (round == 0) ? W0 : W1;
        const float* Em   = (round == 0) ? E0 : E1;
        const int    mode = (round == 2) ? 1 : 0;

#pragma unroll
        for (int g = 0; g < APB / 4; g++) {
            const int a = bl * APB + g * 4 + wv;
            const int start = offs[a];
            const int end   = offs[a + 1];

            float S[NPARA];
#pragma unroll
            for (int k = 0; k < NPARA; k++) S[k] = 0.0f;

            int idx = start + pl;
            float4 r = make_float4(0.f, 0.f, 0.f, 0.f);
            if (idx < end) r = rec[idx];
            for (; idx < end; idx += 8) {
                int nidx = idx + 8;
                float4 rn = r;
                if (nidx < end) rn = rec[nidx];           // prefetch next record
                int jp = __float_as_int(r.w);
                int j  = jp & 0xFFFF;
                int sp = jp >> 16;
                float cj = cin[j * NWAVE + w];            // gather (L1/L2)
                float d2 = r.x * r.x + r.y * r.y + r.z * r.z;
                float d  = sqrtf(d2);
                float cc = __cosf(d * 0.62831853071795864769f); // pi / CUTOFF
                float fc = 0.5f * cc + 0.5f;
                fc = fc * fc;
                float rw = (sp == 0) ? rs0 : (sp == 1) ? rs1 : (sp == 2) ? rs2 : rs3;
                float iw = (sp == 0) ? in0 : (sp == 1) ? in1 : (sp == 2) ? in2 : in3;
                float dr  = d - rw;
                float rad = __expf(iw * dr * dr);
                float q = fc * rad * cj;
                S[0] += q;
                float qx = q * r.x, qy = q * r.y, qz = q * r.z;
                S[1] += qx; S[2] += qy; S[3] += qz;
                S[4]  += qx * r.x; S[5]  += qx * r.y; S[6]  += qx * r.z;
                S[7]  += qy * r.x; S[8]  += qy * r.y; S[9]  += qy * r.z;
                S[10] += qz * r.x; S[11] += qz * r.y; S[12] += qz * r.z;
                r = rn;
            }

#pragma unroll
            for (int k = 0; k < NPARA; k++) {
                S[k] += __shfl_xor(S[k], 8, 64);
                S[k] += __shfl_xor(S[k], 16, 64);
                S[k] += __shfl_xor(S[k], 32, 64);
            }

            if (pl == 0) {
#pragma unroll
                for (int k = 0; k < NPARA; k++) lds_S[wv][w * 16 + k] = S[k];
            }
            __syncthreads();

            float hw0[NPARA], hw1[NPARA];
#pragma unroll
            for (int k = 0; k < NPARA; k++) { hw0[k] = 0.0f; hw1[k] = 0.0f; }
#pragma unroll
            for (int w2 = 0; w2 < NWAVE; w2++) {
                const float* Sw = &lds_S[wv][w2 * 16];
                float4 s0 = *(const float4*)(Sw);        // S[0..3]
                float4 s1 = *(const float4*)(Sw + 4);    // S[4..7]
                float4 s2 = *(const float4*)(Sw + 8);    // S[8..11]
                float  sc = Sw[12];                      // S[12]
                float h00 = hyper[w2 * NORBIT + o0];
                float h01 = hyper[w2 * NORBIT + o1];
                float h10 = hyper[(NWAVE + w2) * NORBIT + o0];
                float h11 = hyper[(NWAVE + w2) * NORBIT + o1];
                float h20 = hyper[(2 * NWAVE + w2) * NORBIT + o0];
                float h21 = hyper[(2 * NWAVE + w2) * NORBIT + o1];
                hw0[0]  += s0.x * h00; hw1[0]  += s0.x * h01;
                hw0[1]  += s0.y * h10; hw1[1]  += s0.y * h11;
                hw0[2]  += s0.z * h10; hw1[2]  += s0.z * h11;
                hw0[3]  += s0.w * h10; hw1[3]  += s0.w * h11;
                hw0[4]  += s1.x * h20; hw1[4]  += s1.x * h21;
                hw0[5]  += s1.y * h20; hw1[5]  += s1.y * h21;
                hw0[6]  += s1.z * h20; hw1[6]  += s1.z * h21;
                hw0[7]  += s1.w * h20; hw1[7]  += s1.w * h21;
                hw0[8]  += s2.x * h20; hw1[8]  += s2.x * h21;
                hw0[9]  += s2.y * h20; hw1[9]  += s2.y * h21;
                hw0[10] += s2.z * h20; hw1[10] += s2.z * h21;
                hw0[11] += s2.w * h20; hw1[11] += s2.w * h21;
                hw0[12] += sc   * h20; hw1[12] += sc   * h21;
            }
            float acc0 = 0.0f, acc1 = 0.0f;
#pragma unroll
            for (int k = 0; k < NPARA; k++) {
                acc0 += hw0[k] * hw0[k];
                acc1 += hw1[k] * hw1[k];
            }

            if (mode == 1) {
                density_out[a * NORBIT + o0] = acc0;
                density_out[a * NORBIT + o1] = acc1;
            } else {
                float part[NWAVE];
#pragma unroll
                for (int w2 = 0; w2 < NWAVE; w2++)
                    part[w2] = acc0 * Wm[o0 * NWAVE + w2] + acc1 * Wm[o1 * NWAVE + w2];
#pragma unroll
                for (int mask = 1; mask < 64; mask <<= 1) {
#pragma unroll
                    for (int w2 = 0; w2 < NWAVE; w2++)
                        part[w2] += __shfl_xor(part[w2], mask, 64);
                }
                if (lane < NWAVE) {
                    int sp = species[a];
                    cout[a * NWAVE + lane] =
                        cin[a * NWAVE + lane] + fast_tanh(part[lane] + Em[sp * NWAVE + lane]);
                }
            }
            __syncthreads();   // lds_S reused by next g / next round
        }
        if (round < 2) {
            __threadfence();
            grid.sync();
            __threadfence();
        }
    }
}

/* ================= fallback: proven separate-kernel path ================= */

__global__ __launch_bounds__(256) void k_hist(const int* __restrict__ atom_index,
                                              int* __restrict__ histpart) {
    const int bl = blockIdx.x, t = threadIdx.x;
    const int b = bl >> 3, c = bl & 7;
    __shared__ int hist[NATOM];
    hist[t] = 0;
    __syncthreads();
    const int base = b * NPP + c * FB_CHUNK;
#pragma unroll
    for (int k = 0; k < FB_CHUNK / 256; k++) {
        int i = atom_index[base + t + k * 256];
        atomicAdd(&hist[i], 1);
    }
    __syncthreads();
    histpart[bl * NATOM + t] = hist[t];
}

__global__ __launch_bounds__(256) void k_offsets(const int* __restrict__ histpart,
                                                 int* __restrict__ startpart,
                                                 int* __restrict__ offs,
                                                 const int* __restrict__ species,
                                                 const float* __restrict__ params,
                                                 float* __restrict__ coeff0) {
    const int b = blockIdx.x, t = threadIdx.x;
    int h[FB_BPB];
    int tot = 0;
#pragma unroll
    for (int c = 0; c < FB_BPB; c++) {
        h[c] = histpart[(b * FB_BPB + c) * NATOM + t];
        tot += h[c];
    }
    __shared__ int scan[NATOM];
    scan[t] = tot;
    __syncthreads();
    for (int d = 1; d < NATOM; d <<= 1) {
        int v = (t >= d) ? scan[t - d] : 0;
        __syncthreads();
        scan[t] += v;
        __syncthreads();
    }
    int run = b * NPP + (scan[t] - tot);
    offs[b * NATOM + t] = run;
    if (b == 0 && t == 0) offs[TOTATOM] = NPAIR;
#pragma unroll
    for (int c = 0; c < FB_BPB; c++) {
        startpart[(b * FB_BPB + c) * NATOM + t] = run;
        run += h[c];
    }
    int a = b * NATOM + t;
    int sp = species[a];
#pragma unroll
    for (int w = 0; w < NWAVE; w++) coeff0[a * NWAVE + w] = params[sp * NWAVE + w];
}

__global__ __launch_bounds__(256) void k_scatter(const int* __restrict__ atom_index,
                                                 const float* __restrict__ cart,
                                                 const float* __restrict__ shifts,
                                                 const int* __restrict__ species,
                                                 const int* __restrict__ startpart,
                                                 float4* __restrict__ rec) {
    const int bl = blockIdx.x, t = threadIdx.x;
    const int b = bl >> 3, c = bl & 7;
    __shared__ int cur[NATOM];
    __shared__ float cx[NATOM], cy[NATOM], cz[NATOM];
    __shared__ int spl[NATOM];
    cur[t] = startpart[bl * NATOM + t];
    const int ag = b * NATOM + t;
    cx[t] = cart[ag * 3 + 0];
    cy[t] = cart[ag * 3 + 1];
    cz[t] = cart[ag * 3 + 2];
    spl[t] = species[ag];
    __syncthreads();
    const int base = b * NPP + c * FB_CHUNK;
#pragma unroll
    for (int k = 0; k < FB_CHUNK / 256; k++) {
        int p = base + t + k * 256;
        int i = atom_index[p];
        int j = atom_index[NPAIR + p];
        float dx = cx[i] - cx[j] + shifts[p * 3 + 0];
        float dy = cy[i] - cy[j] + shifts[p * 3 + 1];
        float dz = cz[i] - cz[j] + shifts[p * 3 + 2];
        int jg = b * NATOM + j;
        int pos = atomicAdd(&cur[i], 1);
        rec[pos] = make_float4(dx, dy, dz, __int_as_float(jg | (spl[j] << 16)));
    }
}

__global__ __launch_bounds__(256) void k_density(const float4* __restrict__ rec,
                                                 const int* __restrict__ offs,
                                                 const float* __restrict__ coeff_in,
                                                 const float* __restrict__ rs,
                                                 const float* __restrict__ inta,
                                                 const float* __restrict__ hyper,
                                                 const float* __restrict__ W,
                                                 const float* __restrict__ E,
                                                 const int* __restrict__ species,
                                                 float* __restrict__ coeff_out,
                                                 float* __restrict__ density_out,
                                                 int mode) {
    const int wv = threadIdx.x >> 6;
    const int lane = threadIdx.x & 63;
    const int a = blockIdx.x * 4 + wv;
    const int pl = lane >> 3;
    const int w  = lane & 7;

    float rs0 = rs[w],      rs1 = rs[8 + w],  rs2 = rs[16 + w], rs3 = rs[24 + w];
    float in0 = inta[w],    in1 = inta[8 + w], in2 = inta[16 + w], in3 = inta[24 + w];

    const int start = offs[a];
    const int end   = offs[a + 1];

    float S[NPARA];
#pragma unroll
    for (int k = 0; k < NPARA; k++) S[k] = 0.0f;

    int idx = start + pl;
    float4 r = make_float4(0.f, 0.f, 0.f, 0.f);
    if (idx < end) r = rec[idx];
    for (; idx < end; idx += 8) {
        int nidx = idx + 8;
        float4 rn = r;
        if (nidx < end) rn = rec[nidx];
        int jp = __float_as_int(r.w);
        int j  = jp & 0xFFFF;
        int sp = jp >> 16;
        float cj = coeff_in[j * NWAVE + w];
        float d2 = r.x * r.x + r.y * r.y + r.z * r.z;
        float d  = sqrtf(d2);
        float c  = __cosf(d * 0.62831853071795864769f);
        float fc = 0.5f * c + 0.5f;
        fc = fc * fc;
        float rw = (sp == 0) ? rs0 : (sp == 1) ? rs1 : (sp == 2) ? rs2 : rs3;
        float iw = (sp == 0) ? in0 : (sp == 1) ? in1 : (sp == 2) ? in2 : in3;
        float dr  = d - rw;
        float rad = __expf(iw * dr * dr);
        float q = fc * rad * cj;
        S[0] += q;
        float qx = q * r.x, qy = q * r.y, qz = q * r.z;
        S[1] += qx; S[2] += qy; S[3] += qz;
        S[4]  += qx * r.x; S[5]  += qx * r.y; S[6]  += qx * r.z;
        S[7]  += qy * r.x; S[8]  += qy * r.y; S[9]  += qy * r.z;
        S[10] += qz * r.x; S[11] += qz * r.y; S[12] += qz * r.z;
        r = rn;
    }

#pragma unroll
    for (int k = 0; k < NPARA; k++) {
        S[k] += __shfl_xor(S[k], 8, 64);
        S[k] += __shfl_xor(S[k], 16, 64);
        S[k] += __shfl_xor(S[k], 32, 64);
    }

    __shared__ float lds_S[4][NWAVE * 16];
    if (pl == 0) {
#pragma unroll
        for (int k = 0; k < NPARA; k++) lds_S[wv][w * 16 + k] = S[k];
    }
    __syncthreads();

    const int o0 = lane, o1 = lane + 64;
    float hw0[NPARA], hw1[NPARA];
#pragma unroll
    for (int k = 0; k < NPARA; k++) { hw0[k] = 0.0f; hw1[k] = 0.0f; }
#pragma unroll
    for (int w2 = 0; w2 < NWAVE; w2++) {
        const float* Sw = &lds_S[wv][w2 * 16];
        float4 s0 = *(const float4*)(Sw);
        float4 s1 = *(const float4*)(Sw + 4);
        float4 s2 = *(const float4*)(Sw + 8);
        float  sc = Sw[12];
        float h00 = hyper[w2 * NORBIT + o0];
        float h01 = hyper[w2 * NORBIT + o1];
        float h10 = hyper[(NWAVE + w2) * NORBIT + o0];
        float h11 = hyper[(NWAVE + w2) * NORBIT + o1];
        float h20 = hyper[(2 * NWAVE + w2) * NORBIT + o0];
        float h21 = hyper[(2 * NWAVE + w2) * NORBIT + o1];
        hw0[0]  += s0.x * h00; hw1[0]  += s0.x * h01;
        hw0[1]  += s0.y * h10; hw1[1]  += s0.y * h11;
        hw0[2]  += s0.z * h10; hw1[2]  += s0.z * h11;
        hw0[3]  += s0.w * h10; hw1[3]  += s0.w * h11;
        hw0[4]  += s1.x * h20; hw1[4]  += s1.x * h21;
        hw0[5]  += s1.y * h20; hw1[5]  += s1.y * h21;
        hw0[6]  += s1.z * h20; hw1[6]  += s1.z * h21;
        hw0[7]  += s1.w * h20; hw1[7]  += s1.w * h21;
        hw0[8]  += s2.x * h20; hw1[8]  += s2.x * h21;
        hw0[9]  += s2.y * h20; hw1[9]  += s2.y * h21;
        hw0[10] += s2.z * h20; hw1[10] += s2.z * h21;
        hw0[11] += s2.w * h20; hw1[11] += s2.w * h21;
        hw0[12] += sc   * h20; hw1[12] += sc   * h21;
    }
    float acc0 = 0.0f, acc1 = 0.0f;
#pragma unroll
    for (int k = 0; k < NPARA; k++) {
        acc0 += hw0[k] * hw0[k];
        acc1 += hw1[k] * hw1[k];
    }

    if (mode == 1) {
        density_out[a * NORBIT + o0] = acc0;
        density_out[a * NORBIT + o1] = acc1;
        return;
    }

    float part[NWAVE];
#pragma unroll
    for (int w2 = 0; w2 < NWAVE; w2++)
        part[w2] = acc0 * W[o0 * NWAVE + w2] + acc1 * W[o1 * NWAVE + w2];
#pragma unroll
    for (int mask = 1; mask < 64; mask <<= 1) {
#pragma unroll
        for (int w2 = 0; w2 < NWAVE; w2++)
            part[w2] += __shfl_xor(part[w2], mask, 64);
    }
    if (lane < NWAVE) {
        int sp = species[a];
        coeff_out[a * NWAVE + lane] =
            coeff_in[a * NWAVE + lane] + fast_tanh(part[lane] + E[sp * NWAVE + lane]);
    }
}

extern "C" void kernel_launch(void* const* d_in, const int* in_sizes, int n_in,
                              void* d_out, int out_size, void* d_ws, size_t ws_size,
                              hipStream_t stream) {
    const float* cart    = (const float*)d_in[0];
    const float* shifts  = (const float*)d_in[1];
    const float* rs      = (const float*)d_in[2];
    const float* inta    = (const float*)d_in[3];
    const float* params  = (const float*)d_in[4];
    const float* hyper   = (const float*)d_in[5];
    const float* w0      = (const float*)d_in[6];
    const float* e0      = (const float*)d_in[7];
    const float* w1      = (const float*)d_in[8];
    const float* e1      = (const float*)d_in[9];
    // d_in[10] = numatoms (unused, always NATOM)
    const int* species    = (const int*)d_in[11];
    const int* atom_index = (const int*)d_in[12];
    float* out = (float*)d_out;

    char* ws = (char*)d_ws;
    float4* rec    = (float4*)ws;  ws += (size_t)NPAIR * 16;            // 8 MiB
    float* coeffA  = (float*)ws;   ws += (size_t)TOTATOM * NWAVE * 4;   // 256 KiB
    float* coeffB  = (float*)ws;   ws += (size_t)TOTATOM * NWAVE * 4;   // 256 KiB
    int* offs      = (int*)ws;     ws += (TOTATOM + 1) * 4;
    ws = (char*)(((uintptr_t)ws + 255) & ~(uintptr_t)255);
    int* histpart  = (int*)ws;     ws += (size_t)NBLK * NATOM * 4;      // 1 MiB
    int* startpart = (int*)ws;     ws += (size_t)NBLK * NATOM * 4;      // 1 MiB

    static int coop_ok = -1;   // -1 unknown, 1 works, 0 rejected
    if (coop_ok != 0) {
        void* args[] = {
            (void*)&atom_index, (void*)&cart, (void*)&shifts, (void*)&species,
            (void*)&rs, (void*)&inta, (void*)&params, (void*)&hyper,
            (void*)&w0, (void*)&e0, (void*)&w1, (void*)&e1,
            (void*)&out, (void*)&rec, (void*)&coeffA, (void*)&coeffB,
            (void*)&offs, (void*)&histpart, (void*)&startpart
        };
        hipError_t err = hipLaunchCooperativeKernel((const void*)k_fused,
                                                    dim3(NBLK), dim3(256),
                                                    args, 0, stream);
        if (err == hipSuccess) { coop_ok = 1; return; }
        coop_ok = 0;           // rejected — fall through to proven path
    }

    k_hist<<<FB_NBLK, 256, 0, stream>>>(atom_index, histpart);
    k_offsets<<<NB, 256, 0, stream>>>(histpart, startpart, offs, species, params, coeffA);
    k_scatter<<<FB_NBLK, 256, 0, stream>>>(atom_index, cart, shifts, species, startpart, rec);

    k_density<<<TOTATOM / 4, 256, 0, stream>>>(rec, offs, coeffA, rs, inta, hyper,
                                               w0, e0, species, coeffB, out, 0);
    k_density<<<TOTATOM / 4, 256, 0, stream>>>(rec, offs, coeffB, rs, inta, hyper,
                                               w1, e1, species, coeffA, out, 0);
    k_density<<<TOTATOM / 4, 256, 0, stream>>>(rec, offs, coeffA, rs, inta, hyper,
                                               w1, e1, species, coeffB, out, 1);
}

// Round 3
// 147.988 us; speedup vs baseline: 1.0135x; 1.0122x over previous
//
#include <hip/hip_runtime.h>
#include <math.h>

#define NTYPE   4
#define NWAVE   8
#define NORBIT  128
#define NEIGH   64
#define NB      32
#define NATOM   256
#define NPP     (NATOM * NEIGH)   /* 16384 pairs per batch */
#define NPAIR   (NB * NPP)        /* 524288 */
#define TOTATOM (NB * NATOM)      /* 8192  */
#define NPARA   13                /* 1 + 3 + 9 */
#define CAP     128               /* slots per atom; P(overflow) ~1e-15 */

#define SC_CHUNK 2048             /* pairs per scatter block */
#define SC_BPB   8                /* scatter blocks per batch */
#define SC_NBLK  (NB * SC_BPB)    /* 256 */

__device__ __forceinline__ float fast_tanh(float x) {
    float ax = fabsf(x);
    float e  = __expf(-2.0f * ax);
    float r  = (1.0f - e) / (1.0f + e);
    return copysignf(r, x);
}

// ---- scatter via global atomic-append (replaces hist+offsets+scatter) ------
__global__ __launch_bounds__(256) void k_scatter(const int* __restrict__ atom_index,
                                                 const float* __restrict__ cart,
                                                 const float* __restrict__ shifts,
                                                 const int* __restrict__ species,
                                                 int* __restrict__ cnt,
                                                 float4* __restrict__ rec) {
    const int bl = blockIdx.x, t = threadIdx.x;
    const int b = bl >> 3, c = bl & 7;
    __shared__ float cx[NATOM], cy[NATOM], cz[NATOM];
    __shared__ int spl[NATOM];
    const int ag = b * NATOM + t;
    cx[t] = cart[ag * 3 + 0];
    cy[t] = cart[ag * 3 + 1];
    cz[t] = cart[ag * 3 + 2];
    spl[t] = species[ag];
    __syncthreads();
    const int base = b * NPP + c * SC_CHUNK;
#pragma unroll
    for (int k = 0; k < SC_CHUNK / 256; k++) {
        int p = base + t + k * 256;
        int i = atom_index[p];
        int j = atom_index[NPAIR + p];
        float dx = cx[i] - cx[j] + shifts[p * 3 + 0];
        float dy = cy[i] - cy[j] + shifts[p * 3 + 1];
        float dz = cz[i] - cz[j] + shifts[p * 3 + 2];
        int ig = b * NATOM + i;
        int jg = b * NATOM + j;
        int pos = atomicAdd(&cnt[ig], 1);
        if (pos < CAP)
            rec[(size_t)ig * CAP + pos] =
                make_float4(dx, dy, dz, __int_as_float(jg | (spl[j] << 16)));
    }
}

// ---- fused obtain() + coeff update -----------------------------------------
// MODE 0: coeff_out = cin + tanh(density @ W + E[species]);  MODE 1: write density.
// INL: round 0 — orbital coeff is params[species[j]][w], held in registers; no gather.
template <int MODE, bool INL>
__global__ __launch_bounds__(256) void k_density(const float4* __restrict__ rec,
                                                 const int* __restrict__ cnt,
                                                 const float* __restrict__ coeff_in,
                                                 const float* __restrict__ rs,
                                                 const float* __restrict__ inta,
                                                 const float* __restrict__ params,
                                                 const float* __restrict__ hyper,
                                                 const float* __restrict__ W,
                                                 const float* __restrict__ E,
                                                 const int* __restrict__ species,
                                                 float* __restrict__ coeff_out,
                                                 float* __restrict__ density_out) {
    const int wv = threadIdx.x >> 6;
    const int lane = threadIdx.x & 63;
    const int a = blockIdx.x * 4 + wv;
    const int pl = lane >> 3;       // pair sub-lane 0..7
    const int w  = lane & 7;        // wave channel 0..7

    // register-resident per-species tables for this lane's w
    float rs0 = rs[w],   rs1 = rs[8 + w],   rs2 = rs[16 + w],   rs3 = rs[24 + w];
    float in0 = inta[w], in1 = inta[8 + w], in2 = inta[16 + w], in3 = inta[24 + w];
    float pm0 = 0.f, pm1 = 0.f, pm2 = 0.f, pm3 = 0.f;
    if (INL) {
        pm0 = params[w];      pm1 = params[8 + w];
        pm2 = params[16 + w]; pm3 = params[24 + w];
    }

    const int n = cnt[a];
    const float4* rbase = rec + (size_t)a * CAP;

    float S[NPARA];
#pragma unroll
    for (int k = 0; k < NPARA; k++) S[k] = 0.0f;

    int idx = pl;
    float4 r = make_float4(0.f, 0.f, 0.f, 0.f);
    if (idx < n) r = rbase[idx];
    for (; idx < n; idx += 8) {
        int nidx = idx + 8;
        float4 rn = r;
        if (nidx < n) rn = rbase[nidx];           // prefetch next record
        int jp = __float_as_int(r.w);
        int sp = jp >> 16;
        float cj;
        if (INL) {
            cj = (sp == 0) ? pm0 : (sp == 1) ? pm1 : (sp == 2) ? pm2 : pm3;
        } else {
            int j = jp & 0xFFFF;
            cj = coeff_in[j * NWAVE + w];         // gather (L1/L2)
        }
        float d2 = r.x * r.x + r.y * r.y + r.z * r.z;
        float d  = sqrtf(d2);
        float c  = __cosf(d * 0.62831853071795864769f); // pi / CUTOFF
        float fc = 0.5f * c + 0.5f;
        fc = fc * fc;
        float rw = (sp == 0) ? rs0 : (sp == 1) ? rs1 : (sp == 2) ? rs2 : rs3;
        float iw = (sp == 0) ? in0 : (sp == 1) ? in1 : (sp == 2) ? in2 : in3;
        float dr  = d - rw;
        float rad = __expf(iw * dr * dr);
        float q = fc * rad * cj;
        S[0] += q;
        float qx = q * r.x, qy = q * r.y, qz = q * r.z;
        S[1] += qx; S[2] += qy; S[3] += qz;
        S[4]  += qx * r.x; S[5]  += qx * r.y; S[6]  += qx * r.z;
        S[7]  += qy * r.x; S[8]  += qy * r.y; S[9]  += qy * r.z;
        S[10] += qz * r.x; S[11] += qz * r.y; S[12] += qz * r.z;
        r = rn;
    }

    // reduce over the 8 pair sub-lanes (lanes sharing w differ in bits 3..5)
#pragma unroll
    for (int k = 0; k < NPARA; k++) {
        S[k] += __shfl_xor(S[k], 8, 64);
        S[k] += __shfl_xor(S[k], 16, 64);
        S[k] += __shfl_xor(S[k], 32, 64);
    }

    // transposed stash: lds_S[wv][w*16 + para]  (stride 16 -> b128-aligned rows)
    __shared__ float lds_S[4][NWAVE * 16];
    if (pl == 0) {
#pragma unroll
        for (int k = 0; k < NPARA; k++) lds_S[wv][w * 16 + k] = S[k];
    }
    __syncthreads();

    // projection with hw-accumulators: hyper read once per (w,ip) -> 48 loads
    const int o0 = lane, o1 = lane + 64;
    float hw0[NPARA], hw1[NPARA];
#pragma unroll
    for (int k = 0; k < NPARA; k++) { hw0[k] = 0.0f; hw1[k] = 0.0f; }
#pragma unroll
    for (int w2 = 0; w2 < NWAVE; w2++) {
        const float* Sw = &lds_S[wv][w2 * 16];
        float4 s0 = *(const float4*)(Sw);        // S[0..3]  (broadcast ds_read_b128)
        float4 s1 = *(const float4*)(Sw + 4);    // S[4..7]
        float4 s2 = *(const float4*)(Sw + 8);    // S[8..11]
        float  sc = Sw[12];                      // S[12]
        float h00 = hyper[w2 * NORBIT + o0];
        float h01 = hyper[w2 * NORBIT + o1];
        float h10 = hyper[(NWAVE + w2) * NORBIT + o0];
        float h11 = hyper[(NWAVE + w2) * NORBIT + o1];
        float h20 = hyper[(2 * NWAVE + w2) * NORBIT + o0];
        float h21 = hyper[(2 * NWAVE + w2) * NORBIT + o1];
        hw0[0]  += s0.x * h00; hw1[0]  += s0.x * h01;
        hw0[1]  += s0.y * h10; hw1[1]  += s0.y * h11;
        hw0[2]  += s0.z * h10; hw1[2]  += s0.z * h11;
        hw0[3]  += s0.w * h10; hw1[3]  += s0.w * h11;
        hw0[4]  += s1.x * h20; hw1[4]  += s1.x * h21;
        hw0[5]  += s1.y * h20; hw1[5]  += s1.y * h21;
        hw0[6]  += s1.z * h20; hw1[6]  += s1.z * h21;
        hw0[7]  += s1.w * h20; hw1[7]  += s1.w * h21;
        hw0[8]  += s2.x * h20; hw1[8]  += s2.x * h21;
        hw0[9]  += s2.y * h20; hw1[9]  += s2.y * h21;
        hw0[10] += s2.z * h20; hw1[10] += s2.z * h21;
        hw0[11] += s2.w * h20; hw1[11] += s2.w * h21;
        hw0[12] += sc   * h20; hw1[12] += sc   * h21;
    }
    float acc0 = 0.0f, acc1 = 0.0f;
#pragma unroll
    for (int k = 0; k < NPARA; k++) {
        acc0 += hw0[k] * hw0[k];
        acc1 += hw1[k] * hw1[k];
    }

    if (MODE == 1) {
        density_out[a * NORBIT + o0] = acc0;
        density_out[a * NORBIT + o1] = acc1;
        return;
    }

    // fused coeff update: part[w] = sum_o density[o] * W[o][w]
    float part[NWAVE];
#pragma unroll
    for (int w2 = 0; w2 < NWAVE; w2++)
        part[w2] = acc0 * W[o0 * NWAVE + w2] + acc1 * W[o1 * NWAVE + w2];
#pragma unroll
    for (int mask = 1; mask < 64; mask <<= 1) {
#pragma unroll
        for (int w2 = 0; w2 < NWAVE; w2++)
            part[w2] += __shfl_xor(part[w2], mask, 64);
    }
    if (lane < NWAVE) {
        int sp = species[a];
        float cin_v;
        if (INL) cin_v = params[sp * NWAVE + lane];
        else     cin_v = coeff_in[a * NWAVE + lane];
        coeff_out[a * NWAVE + lane] =
            cin_v + fast_tanh(part[lane] + E[sp * NWAVE + lane]);
    }
}

extern "C" void kernel_launch(void* const* d_in, const int* in_sizes, int n_in,
                              void* d_out, int out_size, void* d_ws, size_t ws_size,
                              hipStream_t stream) {
    const float* cart    = (const float*)d_in[0];
    const float* shifts  = (const float*)d_in[1];
    const float* rs      = (const float*)d_in[2];
    const float* inta    = (const float*)d_in[3];
    const float* params  = (const float*)d_in[4];
    const float* hyper   = (const float*)d_in[5];
    const float* w0      = (const float*)d_in[6];
    const float* e0      = (const float*)d_in[7];
    const float* w1      = (const float*)d_in[8];
    const float* e1      = (const float*)d_in[9];
    // d_in[10] = numatoms (unused, always NATOM)
    const int* species    = (const int*)d_in[11];
    const int* atom_index = (const int*)d_in[12];
    float* out = (float*)d_out;

    char* ws = (char*)d_ws;
    float4* rec   = (float4*)ws; ws += (size_t)TOTATOM * CAP * 16;     // 16 MiB
    float* coeffA = (float*)ws;  ws += (size_t)TOTATOM * NWAVE * 4;    // 256 KiB
    float* coeffB = (float*)ws;  ws += (size_t)TOTATOM * NWAVE * 4;    // 256 KiB
    int* cnt      = (int*)ws;    ws += (size_t)TOTATOM * 4;            // 32 KiB

    hipMemsetAsync(cnt, 0, (size_t)TOTATOM * 4, stream);
    k_scatter<<<SC_NBLK, 256, 0, stream>>>(atom_index, cart, shifts, species, cnt, rec);

    k_density<0, true ><<<TOTATOM / 4, 256, 0, stream>>>(rec, cnt, nullptr, rs, inta,
                                                         params, hyper, w0, e0, species,
                                                         coeffB, out);
    k_density<0, false><<<TOTATOM / 4, 256, 0, stream>>>(rec, cnt, coeffB, rs, inta,
                                                         params, hyper, w1, e1, species,
                                                         coeffA, out);
    k_density<1, false><<<TOTATOM / 4, 256, 0, stream>>>(rec, cnt, coeffA, rs, inta,
                                                         params, hyper, w1, e1, species,
                                                         nullptr, out);
}